// Round 3
// baseline (7410.718 us; speedup 1.0000x reference)
//
#include <hip/hip_runtime.h>
#include <cmath>

// ---------------- problem constants ----------------
// T=32 B=32 H=W=84 C=3 HID=1024, conv: 84->42->21->11, CONV_OUT=3872
// outputs: logits[1024*7] | baseline[1024] | action[1024] | h_fin[65536] | c_fin[65536]
// activation layouts: conv1 out [n][42][42][32], conv2 out [n][21][21][32],
// conv3 out [n][11][11][32] (=[n][p][co], K-order p*32+co; fc_w1 repacked to match)

// ---------------- ws layout (floats) ----------------
// A      : 14,450,688  conv2 full [1024][21][21][32]; later gx0 @A, gx1 @A+4194304,
//                      fw1t @A+8388608 (3,964,928)
// Bv     :  7,225,344  conv1 chunk [128][42][42][32]; later conv3out [1024][3872]
// fc1    :  1,048,576
// cin    :  1,048,576
// H0     :  1,048,576
// H1     :  1,048,576
// cst    :     65,536
// bsum   :      8,192
// wt     :     19,296   (w1t [27][32] @0, w2t [288][32] @864, w3t [288][32] @10080)

__device__ __forceinline__ float eluf(float v) {
    return v > 0.f ? v : expm1f(v);
}

// weights repacked k-major: wt[(tap*CI+ci)*32 + co]
__global__ __launch_bounds__(256) void repack_w(const float* __restrict__ w1,
    const float* __restrict__ w2, const float* __restrict__ w3, float* __restrict__ wt)
{
    int i = blockIdx.x * 256 + threadIdx.x;
    if (i < 864) {
        int co = i & 31, r = i >> 5;          // r = tap*3+ci
        int tap = r / 3, ci = r - tap * 3;
        int k1 = tap / 3, k2 = tap - k1 * 3;
        wt[i] = w1[co * 27 + ci * 9 + k1 * 3 + k2];
    } else if (i < 10080) {
        int o = i - 864;
        int co = o & 31, r = o >> 5;          // r = tap*32+ci
        int tap = r >> 5, ci = r & 31;
        int k1 = tap / 3, k2 = tap - k1 * 3;
        wt[i] = w2[co * 288 + ci * 9 + k1 * 3 + k2];
    } else if (i < 19296) {
        int o = i - 10080;
        int co = o & 31, r = o >> 5;
        int tap = r >> 5, ci = r & 31;
        int k1 = tap / 3, k2 = tap - k1 * 3;
        wt[i] = w3[co * 288 + ci * 9 + k1 * 3 + k2];
    }
}

__global__ __launch_bounds__(256) void bsum_k(const float* __restrict__ bih0,
    const float* __restrict__ bhh0, const float* __restrict__ bih1,
    const float* __restrict__ bhh1, float* __restrict__ bsum)
{
    int i = blockIdx.x * 256 + threadIdx.x;
    if (i < 4096) bsum[i] = bih0[i] + bhh0[i];
    else if (i < 8192) bsum[i] = bih1[i - 4096] + bhh1[i - 4096];
}

// conv1: frame [n][h][w][3] -> out [nl][ox][oy][32], 42x42, stride2 pad1, ELU
__global__ __launch_bounds__(256) void conv1_k(const float* __restrict__ frame,
    const float* __restrict__ w1t, const float* __restrict__ b1,
    float* __restrict__ out, int n0)
{
    __shared__ float As[27][132];
    __shared__ float Bs[27][32];
    int tid = threadIdx.x;
    if (tid < 216) ((float4*)Bs)[tid] = ((const float4*)w1t)[tid];

    int p0 = blockIdx.x << 7;
    int pxl = tid & 127;
    int half = tid >> 7;
    {
        int p = p0 + pxl;
        int nl = p / 1764;
        int rem = p - nl * 1764;
        int ox = rem / 42;
        int oy = rem - ox * 42;
        const float* fr = frame + (size_t)(n0 + nl) * 21168;
        for (int tap = half; tap < 9; tap += 2) {
            int k1 = tap / 3, k2 = tap - k1 * 3;
            int u = 2 * ox - 1 + k1;
            int v = 2 * oy - 1 + k2;
            bool ok = (u >= 0) && (u < 84) && (v >= 0) && (v < 84);
            int uc = ok ? u : 0, vc = ok ? v : 0;
            const float* fp = fr + (vc * 84 + uc) * 3;
            float x0 = fp[0], x1 = fp[1], x2 = fp[2];
            if (!ok) { x0 = 0.f; x1 = 0.f; x2 = 0.f; }
            As[tap * 3 + 0][pxl] = x0;
            As[tap * 3 + 1][pxl] = x1;
            As[tap * 3 + 2][pxl] = x2;
        }
    }
    __syncthreads();

    int tx = tid & 7, ty = tid >> 3;
    float acc[4][4];
#pragma unroll
    for (int i = 0; i < 4; i++)
#pragma unroll
        for (int j = 0; j < 4; j++) acc[i][j] = 0.f;

#pragma unroll 9
    for (int k = 0; k < 27; k++) {
        float4 a = *(const float4*)&As[k][ty << 2];
        float4 b = *(const float4*)&Bs[k][tx << 2];
        acc[0][0] = fmaf(a.x, b.x, acc[0][0]); acc[0][1] = fmaf(a.x, b.y, acc[0][1]);
        acc[0][2] = fmaf(a.x, b.z, acc[0][2]); acc[0][3] = fmaf(a.x, b.w, acc[0][3]);
        acc[1][0] = fmaf(a.y, b.x, acc[1][0]); acc[1][1] = fmaf(a.y, b.y, acc[1][1]);
        acc[1][2] = fmaf(a.y, b.z, acc[1][2]); acc[1][3] = fmaf(a.y, b.w, acc[1][3]);
        acc[2][0] = fmaf(a.z, b.x, acc[2][0]); acc[2][1] = fmaf(a.z, b.y, acc[2][1]);
        acc[2][2] = fmaf(a.z, b.z, acc[2][2]); acc[2][3] = fmaf(a.z, b.w, acc[2][3]);
        acc[3][0] = fmaf(a.w, b.x, acc[3][0]); acc[3][1] = fmaf(a.w, b.y, acc[3][1]);
        acc[3][2] = fmaf(a.w, b.z, acc[3][2]); acc[3][3] = fmaf(a.w, b.w, acc[3][3]);
    }

    float4 bc = *(const float4*)(b1 + (tx << 2));
#pragma unroll
    for (int i = 0; i < 4; i++) {
        float4 o;
        o.x = eluf(acc[i][0] + bc.x);
        o.y = eluf(acc[i][1] + bc.y);
        o.z = eluf(acc[i][2] + bc.z);
        o.w = eluf(acc[i][3] + bc.w);
        *(float4*)(out + (size_t)(p0 + (ty << 2) + i) * 32 + (tx << 2)) = o;
    }
}

// conv2/conv3: in [n][IS][IS][32] -> out [n+off][OS][OS][32], stride2 pad1, ELU
template<int IS, int OS>
__global__ __launch_bounds__(256) void convg_k(const float* __restrict__ in,
    const float* __restrict__ wtb, const float* __restrict__ bias,
    float* __restrict__ out, int pOff)
{
    __shared__ float Bs[288 * 32];
    __shared__ float As[32][132];
    int tid = threadIdx.x;
    {
        const float4* src = (const float4*)wtb;
        float4* dst = (float4*)Bs;
#pragma unroll
        for (int r = 0; r < 9; r++) dst[tid + r * 256] = src[tid + r * 256];
    }
    const int OS2 = OS * OS;
    int p0 = blockIdx.x << 7;
    int c4 = tid & 7;
    int pn[4], pox[4], poy[4];
#pragma unroll
    for (int i = 0; i < 4; i++) {
        int px = (tid >> 3) + (i << 5);
        int p = p0 + px;
        int n = p / OS2;
        int rem = p - n * OS2;
        int ox = rem / OS;
        pn[i] = n; pox[i] = ox; poy[i] = rem - ox * OS;
    }

    int tx = tid & 7, ty = tid >> 3;
    float acc[4][4];
#pragma unroll
    for (int i = 0; i < 4; i++)
#pragma unroll
        for (int j = 0; j < 4; j++) acc[i][j] = 0.f;

    for (int k1 = 0; k1 < 3; k1++) {
        for (int k2 = 0; k2 < 3; k2++) {
            __syncthreads();
#pragma unroll
            for (int i = 0; i < 4; i++) {
                int px = (tid >> 3) + (i << 5);
                int u = 2 * pox[i] - 1 + k1;
                int v = 2 * poy[i] - 1 + k2;
                bool ok = (u >= 0) && (u < IS) && (v >= 0) && (v < IS);
                int uc = ok ? u : 0, vc = ok ? v : 0;
                float4 val = *(const float4*)(in +
                    ((size_t)((pn[i] * IS + uc) * IS + vc)) * 32 + (c4 << 2));
                if (!ok) { val.x = 0.f; val.y = 0.f; val.z = 0.f; val.w = 0.f; }
                As[(c4 << 2) + 0][px] = val.x;
                As[(c4 << 2) + 1][px] = val.y;
                As[(c4 << 2) + 2][px] = val.z;
                As[(c4 << 2) + 3][px] = val.w;
            }
            __syncthreads();
            const float* bsrc = Bs + (size_t)((k1 * 3 + k2) << 5) * 32;
#pragma unroll 8
            for (int k = 0; k < 32; k++) {
                float4 a = *(const float4*)&As[k][ty << 2];
                float4 b = *(const float4*)&bsrc[(k << 5) + (tx << 2)];
                acc[0][0] = fmaf(a.x, b.x, acc[0][0]); acc[0][1] = fmaf(a.x, b.y, acc[0][1]);
                acc[0][2] = fmaf(a.x, b.z, acc[0][2]); acc[0][3] = fmaf(a.x, b.w, acc[0][3]);
                acc[1][0] = fmaf(a.y, b.x, acc[1][0]); acc[1][1] = fmaf(a.y, b.y, acc[1][1]);
                acc[1][2] = fmaf(a.y, b.z, acc[1][2]); acc[1][3] = fmaf(a.y, b.w, acc[1][3]);
                acc[2][0] = fmaf(a.z, b.x, acc[2][0]); acc[2][1] = fmaf(a.z, b.y, acc[2][1]);
                acc[2][2] = fmaf(a.z, b.z, acc[2][2]); acc[2][3] = fmaf(a.z, b.w, acc[2][3]);
                acc[3][0] = fmaf(a.w, b.x, acc[3][0]); acc[3][1] = fmaf(a.w, b.y, acc[3][1]);
                acc[3][2] = fmaf(a.w, b.z, acc[3][2]); acc[3][3] = fmaf(a.w, b.w, acc[3][3]);
            }
        }
    }

    float4 bc = *(const float4*)(bias + (tx << 2));
#pragma unroll
    for (int i = 0; i < 4; i++) {
        float4 o;
        o.x = eluf(acc[i][0] + bc.x);
        o.y = eluf(acc[i][1] + bc.y);
        o.z = eluf(acc[i][2] + bc.z);
        o.w = eluf(acc[i][3] + bc.w);
        *(float4*)(out + (size_t)(pOff + p0 + (ty << 2) + i) * 32 + (tx << 2)) = o;
    }
}

// fw1t[h][p*32+co] = fw1[h][co*121+p]  (match conv3 K-order)
__global__ __launch_bounds__(256) void repack_fw1(const float* __restrict__ fw1,
    float* __restrict__ fw1t)
{
    __shared__ float row[3872];
    int h = blockIdx.x;
    const float* src = fw1 + (size_t)h * 3872;
    for (int j = threadIdx.x; j < 3872; j += 256) row[j] = src[j];
    __syncthreads();
    float* dst = fw1t + (size_t)h * 3872;
    for (int j = threadIdx.x; j < 3872; j += 256) {
        int p = j >> 5, co = j & 31;
        dst[j] = row[co * 121 + p];
    }
}

// C[m,n] (+)= sum_k A[m*K+k] * Bm[n*K+k]
// 128x128 tile, 8x8/thread, dbuf LDS, 1 barrier/tile.
// grid.x = Mt*Nt decoded nt = bid % Nt (XCD-local B-tiles), grid.z = splitk
__global__ __launch_bounds__(256, 4) void gemm128(const float* __restrict__ A,
    const float* __restrict__ Bm, float* __restrict__ C,
    int M, int N, int K, int Nt, int kchunk, int splitk)
{
    __shared__ float As[2][16][132];
    __shared__ float Bs[2][16][132];
    int tid = threadIdx.x;
    int bid = blockIdx.x;
    int nt = bid % Nt, mt = bid / Nt;
    int n0 = nt << 7, m0 = mt << 7;
    int kbeg = blockIdx.z * kchunk;
    int kend = kbeg + kchunk;
    if (kend > K) kend = K;
    int T = (kend - kbeg) >> 4;

    int tx = tid & 15, ty = tid >> 4;
    // staging indices: 2 float4 each for A and B
    int r0 = tid >> 2, kc0 = (tid & 3) << 2;          // i = tid
    int r1 = (tid + 256) >> 2, kc1 = kc0;             // i = tid+256 (same kc)
    const float* a0p = A + (size_t)(m0 + r0) * K + kbeg + kc0;
    const float* a1p = A + (size_t)(m0 + r1) * K + kbeg + kc1;
    const float* b0p = Bm + (size_t)(n0 + r0) * K + kbeg + kc0;
    const float* b1p = Bm + (size_t)(n0 + r1) * K + kbeg + kc1;

    float acc[8][8];
#pragma unroll
    for (int i = 0; i < 8; i++)
#pragma unroll
        for (int j = 0; j < 8; j++) acc[i][j] = 0.f;

    float4 pa0 = *(const float4*)a0p;
    float4 pa1 = *(const float4*)a1p;
    float4 pb0 = *(const float4*)b0p;
    float4 pb1 = *(const float4*)b1p;
    As[0][kc0 + 0][r0] = pa0.x; As[0][kc0 + 1][r0] = pa0.y;
    As[0][kc0 + 2][r0] = pa0.z; As[0][kc0 + 3][r0] = pa0.w;
    As[0][kc1 + 0][r1] = pa1.x; As[0][kc1 + 1][r1] = pa1.y;
    As[0][kc1 + 2][r1] = pa1.z; As[0][kc1 + 3][r1] = pa1.w;
    Bs[0][kc0 + 0][r0] = pb0.x; Bs[0][kc0 + 1][r0] = pb0.y;
    Bs[0][kc0 + 2][r0] = pb0.z; Bs[0][kc0 + 3][r0] = pb0.w;
    Bs[0][kc1 + 0][r1] = pb1.x; Bs[0][kc1 + 1][r1] = pb1.y;
    Bs[0][kc1 + 2][r1] = pb1.z; Bs[0][kc1 + 3][r1] = pb1.w;

    int p = 0;
    for (int t = 0; t < T; t++) {
        __syncthreads();               // buf p valid; buf 1-p free
        bool more = (t + 1 < T);
        if (more) {
            int ko = (t + 1) << 4;
            pa0 = *(const float4*)(a0p + ko);
            pa1 = *(const float4*)(a1p + ko);
            pb0 = *(const float4*)(b0p + ko);
            pb1 = *(const float4*)(b1p + ko);
        }
#pragma unroll
        for (int k = 0; k < 16; k++) {
            float a[8], b[8];
            *(float4*)&a[0] = *(const float4*)&As[p][k][ty << 2];
            *(float4*)&a[4] = *(const float4*)&As[p][k][64 + (ty << 2)];
            *(float4*)&b[0] = *(const float4*)&Bs[p][k][tx << 2];
            *(float4*)&b[4] = *(const float4*)&Bs[p][k][64 + (tx << 2)];
#pragma unroll
            for (int i = 0; i < 8; i++)
#pragma unroll
                for (int j = 0; j < 8; j++) acc[i][j] = fmaf(a[i], b[j], acc[i][j]);
        }
        if (more) {
            int q = p ^ 1;
            As[q][kc0 + 0][r0] = pa0.x; As[q][kc0 + 1][r0] = pa0.y;
            As[q][kc0 + 2][r0] = pa0.z; As[q][kc0 + 3][r0] = pa0.w;
            As[q][kc1 + 0][r1] = pa1.x; As[q][kc1 + 1][r1] = pa1.y;
            As[q][kc1 + 2][r1] = pa1.z; As[q][kc1 + 3][r1] = pa1.w;
            Bs[q][kc0 + 0][r0] = pb0.x; Bs[q][kc0 + 1][r0] = pb0.y;
            Bs[q][kc0 + 2][r0] = pb0.z; Bs[q][kc0 + 3][r0] = pb0.w;
            Bs[q][kc1 + 0][r1] = pb1.x; Bs[q][kc1 + 1][r1] = pb1.y;
            Bs[q][kc1 + 2][r1] = pb1.z; Bs[q][kc1 + 3][r1] = pb1.w;
            p = q;
        }
    }

#pragma unroll
    for (int i = 0; i < 8; i++) {
        int row = m0 + ((i < 4) ? ((ty << 2) + i) : (64 + (ty << 2) + i - 4));
        float* cp0 = C + (size_t)row * N + n0 + (tx << 2);
        float* cp1 = cp0 + 64;
        if (splitk > 1) {
            atomicAdd(cp0 + 0, acc[i][0]); atomicAdd(cp0 + 1, acc[i][1]);
            atomicAdd(cp0 + 2, acc[i][2]); atomicAdd(cp0 + 3, acc[i][3]);
            atomicAdd(cp1 + 0, acc[i][4]); atomicAdd(cp1 + 1, acc[i][5]);
            atomicAdd(cp1 + 2, acc[i][6]); atomicAdd(cp1 + 3, acc[i][7]);
        } else {
            float4 s0; s0.x = acc[i][0]; s0.y = acc[i][1]; s0.z = acc[i][2]; s0.w = acc[i][3];
            float4 s1; s1.x = acc[i][4]; s1.y = acc[i][5]; s1.z = acc[i][6]; s1.w = acc[i][7];
            *(float4*)cp0 = s0;
            *(float4*)cp1 = s1;
        }
    }
}

__global__ __launch_bounds__(256) void bias_relu(float* __restrict__ x,
    const float* __restrict__ b, int total)
{
    int i = blockIdx.x * 256 + threadIdx.x;
    if (i < total) {
        float v = x[i] + b[i & 1023];
        x[i] = v > 0.f ? v : 0.f;
    }
}

// one LSTM step for one layer. grid 512: bid = jblk*2 + bbhalf
// block: bl=tid&15 (row), q=(tid>>4)&3 (unit of 4), s=tid>>6 (k-quarter)
__global__ __launch_bounds__(256) void lstm_step(
    const float* __restrict__ gx,      // [1024][4096] rows t*32+b
    const float* __restrict__ whh,     // [4096][1024]
    const float* __restrict__ bsum,    // [4096]
    const float* __restrict__ hprev,   // rows b*1024 (pre-offset for t/layer)
    const float* __restrict__ cprev,   // idx b*1024+j (pre-offset for layer)
    float* __restrict__ cout,          // idx b*1024+j
    float* __restrict__ Hout,          // rows t*32+b
    const unsigned char* __restrict__ dmask, // &done[t*32] as bytes
    int t)
{
    __shared__ float Hs[16][260];
    __shared__ float part[3][64][4];
    int tid = threadIdx.x;
    int jblk = blockIdx.x >> 1;
    int bb = (blockIdx.x & 1) << 4;
    int bl = tid & 15;
    int q  = (tid >> 4) & 3;
    int s  = tid >> 6;
    int j = (jblk << 2) + q;
    const float* wi = whh + (size_t)j * 1024;
    const float* wf = wi + (size_t)1024 * 1024;
    const float* wg = wf + (size_t)1024 * 1024;
    const float* wo = wg + (size_t)1024 * 1024;
    float a0 = 0.f, a1 = 0.f, a2 = 0.f, a3 = 0.f;

    for (int kt = 0; kt < 4; kt++) {
        if (kt) __syncthreads();
#pragma unroll
        for (int rep = 0; rep < 4; rep++) {
            int id = tid + (rep << 8);
            int r = id >> 6;
            int c4 = id & 63;
            float4 h4 = *(const float4*)(hprev + (size_t)(bb + r) * 1024 + (kt << 8) + (c4 << 2));
            float nd = dmask[bb + r] ? 0.f : 1.f;
            h4.x *= nd; h4.y *= nd; h4.z *= nd; h4.w *= nd;
            *(float4*)&Hs[r][c4 << 2] = h4;
        }
        __syncthreads();
#pragma unroll
        for (int kq = 0; kq < 16; kq++) {
            int kl = (s << 6) + (kq << 2);
            float4 h4 = *(const float4*)&Hs[bl][kl];
            int kG = (kt << 8) + kl;
            float4 w0 = *(const float4*)(wi + kG);
            float4 w1 = *(const float4*)(wf + kG);
            float4 w2 = *(const float4*)(wg + kG);
            float4 w3 = *(const float4*)(wo + kG);
            a0 = fmaf(h4.x, w0.x, fmaf(h4.y, w0.y, fmaf(h4.z, w0.z, fmaf(h4.w, w0.w, a0))));
            a1 = fmaf(h4.x, w1.x, fmaf(h4.y, w1.y, fmaf(h4.z, w1.z, fmaf(h4.w, w1.w, a1))));
            a2 = fmaf(h4.x, w2.x, fmaf(h4.y, w2.y, fmaf(h4.z, w2.z, fmaf(h4.w, w2.w, a2))));
            a3 = fmaf(h4.x, w3.x, fmaf(h4.y, w3.y, fmaf(h4.z, w3.z, fmaf(h4.w, w3.w, a3))));
        }
    }
    if (s) {
        float4 pv; pv.x = a0; pv.y = a1; pv.z = a2; pv.w = a3;
        *(float4*)&part[s - 1][tid & 63][0] = pv;
    }
    __syncthreads();
    if (!s) {
#pragma unroll
        for (int r = 0; r < 3; r++) {
            float4 pv = *(const float4*)&part[r][tid][0];
            a0 += pv.x; a1 += pv.y; a2 += pv.z; a3 += pv.w;
        }
        int b = bb + bl;
        int row = (t << 5) + b;
        const float* gp = gx + (size_t)row * 4096 + j;
        float g0 = a0 + gp[0]    + bsum[j];
        float g1 = a1 + gp[1024] + bsum[j + 1024];
        float g2 = a2 + gp[2048] + bsum[j + 2048];
        float g3 = a3 + gp[3072] + bsum[j + 3072];
        float nd = dmask[b] ? 0.f : 1.f;
        float cp = cprev[(size_t)b * 1024 + j] * nd;
        float si = 1.f / (1.f + expf(-g0));
        float sf = 1.f / (1.f + expf(-g1));
        float so = 1.f / (1.f + expf(-g3));
        float cn = sf * cp + si * tanhf(g2);
        float hn = so * tanhf(cn);
        cout[(size_t)b * 1024 + j] = cn;
        Hout[(size_t)row * 1024 + j] = hn;
    }
}

__global__ __launch_bounds__(256) void heads_k(const float* __restrict__ Hc,
    const float* __restrict__ pw, const float* __restrict__ pb,
    const float* __restrict__ bw, const float* __restrict__ bbias,
    float* __restrict__ out)
{
    __shared__ float red[8][264];
    int n = blockIdx.x, tid = threadIdx.x;
    float4 x4 = *(const float4*)(Hc + (size_t)n * 1024 + (tid << 2));
#pragma unroll
    for (int a = 0; a < 7; a++) {
        float4 w4 = *(const float4*)(pw + (size_t)a * 1024 + (tid << 2));
        red[a][tid] = x4.x * w4.x + x4.y * w4.y + x4.z * w4.z + x4.w * w4.w;
    }
    {
        float4 w4 = *(const float4*)(bw + (tid << 2));
        red[7][tid] = x4.x * w4.x + x4.y * w4.y + x4.z * w4.z + x4.w * w4.w;
    }
    __syncthreads();
    for (int off = 128; off > 0; off >>= 1) {
        if (tid < off) {
#pragma unroll
            for (int a = 0; a < 8; a++) red[a][tid] += red[a][tid + off];
        }
        __syncthreads();
    }
    if (tid == 0) {
        float best = -1e30f; int bi = 0;
        for (int a = 0; a < 7; a++) {
            float L = red[a][0] + pb[a];
            out[n * 7 + a] = L;
            if (L > best) { best = L; bi = a; }
        }
        out[7168 + n] = red[7][0] + bbias[0];
        out[8192 + n] = (float)bi;
    }
}

__global__ __launch_bounds__(256) void final_copy(const float* __restrict__ H0,
    const float* __restrict__ H1, const float* __restrict__ cst, float* __restrict__ out)
{
    int i = blockIdx.x * 256 + threadIdx.x;   // 131072 exact
    if (i < 65536) {
        int l = i >> 15;
        int rem = i & 32767;
        const float* H = l ? H1 : H0;
        out[9216 + i] = H[(size_t)(31 * 32) * 1024 + rem];
    } else {
        out[74752 + (i - 65536)] = cst[i - 65536];
    }
}

extern "C" void kernel_launch(void* const* d_in, const int* in_sizes, int n_in,
                              void* d_out, int out_size, void* d_ws, size_t ws_size,
                              hipStream_t stream)
{
    (void)in_sizes; (void)n_in; (void)out_size; (void)ws_size;
    const float* frame = (const float*)d_in[0];
    const unsigned char* done8 = (const unsigned char*)d_in[1];
    const float* h0   = (const float*)d_in[2];
    const float* c0   = (const float*)d_in[3];
    const float* cw1  = (const float*)d_in[4];
    const float* cb1  = (const float*)d_in[5];
    const float* cw2  = (const float*)d_in[6];
    const float* cb2  = (const float*)d_in[7];
    const float* cw3  = (const float*)d_in[8];
    const float* cb3  = (const float*)d_in[9];
    const float* fw1  = (const float*)d_in[10];
    const float* fb1  = (const float*)d_in[11];
    const float* fw2  = (const float*)d_in[12];
    const float* fb2  = (const float*)d_in[13];
    const float* wih0 = (const float*)d_in[14];
    const float* whh0 = (const float*)d_in[15];
    const float* bih0 = (const float*)d_in[16];
    const float* bhh0 = (const float*)d_in[17];
    const float* wih1 = (const float*)d_in[18];
    const float* whh1 = (const float*)d_in[19];
    const float* bih1 = (const float*)d_in[20];
    const float* bhh1 = (const float*)d_in[21];
    const float* pw   = (const float*)d_in[22];
    const float* pb   = (const float*)d_in[23];
    const float* bw   = (const float*)d_in[24];
    const float* bbias= (const float*)d_in[25];

    float* ws   = (float*)d_ws;
    float* A    = ws;                      // 14,450,688
    float* Bv   = A + 14450688;            //  7,225,344
    float* fc1  = Bv + 7225344;            //  1,048,576
    float* cin  = fc1 + 1048576;           //  1,048,576
    float* H0   = cin + 1048576;           //  1,048,576
    float* H1   = H0 + 1048576;            //  1,048,576
    float* cst  = H1 + 1048576;            //     65,536
    float* bsum = cst + 65536;             //      8,192
    float* wt   = bsum + 8192;             //     19,296
    float* gx0 = A;
    float* gx1 = A + 4194304;
    float* fw1t = A + 8388608;             //  3,964,928 (dead conv2 space)
    float* conv2f = A;
    float* conv3o = Bv;
    float* out = (float*)d_out;

    repack_w<<<76, 256, 0, stream>>>(cw1, cw2, cw3, wt);
    bsum_k<<<32, 256, 0, stream>>>(bih0, bhh0, bih1, bhh1, bsum);

    for (int ch = 0; ch < 8; ch++) {
        conv1_k<<<1764, 256, 0, stream>>>(frame, wt, cb1, Bv, ch * 128);
        convg_k<42, 21><<<441, 256, 0, stream>>>(Bv, wt + 864, cb2, conv2f, ch * 128 * 441);
    }
    convg_k<21, 11><<<968, 256, 0, stream>>>(conv2f, wt + 10080, cb3, conv3o, 0);
    repack_fw1<<<1024, 256, 0, stream>>>(fw1, fw1t);

    hipMemsetAsync(fc1, 0, (size_t)1048576 * 4, stream);
    hipMemsetAsync(cin, 0, (size_t)1048576 * 4, stream);
    // FC1: M=1024 N=1024 K=3872, Nt=8 -> grid 64 x splitk4 (kchunk 976 mult of 16)
    { dim3 g(64, 1, 4); gemm128<<<g, 256, 0, stream>>>(conv3o, fw1t, fc1, 1024, 1024, 3872, 8, 976, 4); }
    bias_relu<<<4096, 256, 0, stream>>>(fc1, fb1, 1048576);
    { dim3 g(64, 1, 2); gemm128<<<g, 256, 0, stream>>>(fc1, fw2, cin, 1024, 1024, 1024, 8, 512, 2); }
    bias_relu<<<4096, 256, 0, stream>>>(cin, fb2, 1048576);

    // gx: M=1024 N=4096 K=1024, Nt=32 -> grid 256, no splitk
    { dim3 g(256, 1, 1); gemm128<<<g, 256, 0, stream>>>(cin, wih0, gx0, 1024, 4096, 1024, 32, 1024, 1); }
    for (int t = 0; t < 32; t++) {
        const float* hp = t ? (H0 + (size_t)(t - 1) * 32768) : h0;
        const float* cp = t ? cst : c0;
        lstm_step<<<512, 256, 0, stream>>>(gx0, whh0, bsum, hp, cp, cst, H0, done8 + t * 32, t);
    }
    { dim3 g(256, 1, 1); gemm128<<<g, 256, 0, stream>>>(H0, wih1, gx1, 1024, 4096, 1024, 32, 1024, 1); }
    for (int t = 0; t < 32; t++) {
        const float* hp = t ? (H1 + (size_t)(t - 1) * 32768) : (h0 + 32768);
        const float* cp = t ? (cst + 32768) : (c0 + 32768);
        lstm_step<<<512, 256, 0, stream>>>(gx1, whh1, bsum + 4096, hp, cp, cst + 32768, H1, done8 + t * 32, t);
    }
    heads_k<<<1024, 256, 0, stream>>>(H1, pw, pb, bw, bbias, out);
    final_copy<<<512, 256, 0, stream>>>(H0, H1, cst, out);
}

// Round 4
// 2652.790 us; speedup vs baseline: 2.7936x; 2.7936x over previous
//
#include <hip/hip_runtime.h>
#include <cmath>

// ---------------- problem constants ----------------
// T=32 B=32 H=W=84 C=3 HID=1024, conv: 84->42->21->11, CONV_OUT=3872
// outputs: logits[1024*7] | baseline[1024] | action[1024] | h_fin[65536] | c_fin[65536]
// activation layouts: conv1 out [n][42][42][32], conv2 out [n][21][21][32],
// conv3 out [n][11][11][32] (=[n][p][co], K-order p*32+co; fc_w1 repacked to match)

// ---------------- ws layout (floats) ----------------
// A      : 14,450,688  conv2 full [1024][21][21][32]; later gx0 @A, gx1 @A+4194304,
//                      fw1t @A+8388608 (3,964,928)
// Bv     :  7,225,344  conv1 chunk [128][42][42][32]; later conv3out [1024][3872]
// fc1    :  1,048,576
// cin    :  1,048,576
// H0     :  1,048,576
// H1     :  1,048,576
// cst    :     65,536
// bsum   :      8,192
// wt     :     19,296   (w1t [27][32] @0, w2t [288][32] @864, w3t [288][32] @10080)

__device__ __forceinline__ float eluf(float v) {
    return v > 0.f ? v : expm1f(v);
}

// weights repacked k-major: wt[(tap*CI+ci)*32 + co]
__global__ __launch_bounds__(256) void repack_w(const float* __restrict__ w1,
    const float* __restrict__ w2, const float* __restrict__ w3, float* __restrict__ wt)
{
    int i = blockIdx.x * 256 + threadIdx.x;
    if (i < 864) {
        int co = i & 31, r = i >> 5;          // r = tap*3+ci
        int tap = r / 3, ci = r - tap * 3;
        int k1 = tap / 3, k2 = tap - k1 * 3;
        wt[i] = w1[co * 27 + ci * 9 + k1 * 3 + k2];
    } else if (i < 10080) {
        int o = i - 864;
        int co = o & 31, r = o >> 5;          // r = tap*32+ci
        int tap = r >> 5, ci = r & 31;
        int k1 = tap / 3, k2 = tap - k1 * 3;
        wt[i] = w2[co * 288 + ci * 9 + k1 * 3 + k2];
    } else if (i < 19296) {
        int o = i - 10080;
        int co = o & 31, r = o >> 5;
        int tap = r >> 5, ci = r & 31;
        int k1 = tap / 3, k2 = tap - k1 * 3;
        wt[i] = w3[co * 288 + ci * 9 + k1 * 3 + k2];
    }
}

__global__ __launch_bounds__(256) void bsum_k(const float* __restrict__ bih0,
    const float* __restrict__ bhh0, const float* __restrict__ bih1,
    const float* __restrict__ bhh1, float* __restrict__ bsum)
{
    int i = blockIdx.x * 256 + threadIdx.x;
    if (i < 4096) bsum[i] = bih0[i] + bhh0[i];
    else if (i < 8192) bsum[i] = bih1[i - 4096] + bhh1[i - 4096];
}

// conv1: frame [n][h][w][3] -> out [nl][ox][oy][32], 42x42, stride2 pad1, ELU
__global__ __launch_bounds__(256) void conv1_k(const float* __restrict__ frame,
    const float* __restrict__ w1t, const float* __restrict__ b1,
    float* __restrict__ out, int n0)
{
    __shared__ float As[27][132];
    __shared__ float Bs[27][32];
    int tid = threadIdx.x;
    if (tid < 216) ((float4*)Bs)[tid] = ((const float4*)w1t)[tid];

    int p0 = blockIdx.x << 7;
    int pxl = tid & 127;
    int half = tid >> 7;
    {
        int p = p0 + pxl;
        int nl = p / 1764;
        int rem = p - nl * 1764;
        int ox = rem / 42;
        int oy = rem - ox * 42;
        const float* fr = frame + (size_t)(n0 + nl) * 21168;
        for (int tap = half; tap < 9; tap += 2) {
            int k1 = tap / 3, k2 = tap - k1 * 3;
            int u = 2 * ox - 1 + k1;
            int v = 2 * oy - 1 + k2;
            bool ok = (u >= 0) && (u < 84) && (v >= 0) && (v < 84);
            int uc = ok ? u : 0, vc = ok ? v : 0;
            const float* fp = fr + (vc * 84 + uc) * 3;
            float x0 = fp[0], x1 = fp[1], x2 = fp[2];
            if (!ok) { x0 = 0.f; x1 = 0.f; x2 = 0.f; }
            As[tap * 3 + 0][pxl] = x0;
            As[tap * 3 + 1][pxl] = x1;
            As[tap * 3 + 2][pxl] = x2;
        }
    }
    __syncthreads();

    int tx = tid & 7, ty = tid >> 3;
    float acc[4][4];
#pragma unroll
    for (int i = 0; i < 4; i++)
#pragma unroll
        for (int j = 0; j < 4; j++) acc[i][j] = 0.f;

#pragma unroll 9
    for (int k = 0; k < 27; k++) {
        float4 a = *(const float4*)&As[k][ty << 2];
        float4 b = *(const float4*)&Bs[k][tx << 2];
        acc[0][0] = fmaf(a.x, b.x, acc[0][0]); acc[0][1] = fmaf(a.x, b.y, acc[0][1]);
        acc[0][2] = fmaf(a.x, b.z, acc[0][2]); acc[0][3] = fmaf(a.x, b.w, acc[0][3]);
        acc[1][0] = fmaf(a.y, b.x, acc[1][0]); acc[1][1] = fmaf(a.y, b.y, acc[1][1]);
        acc[1][2] = fmaf(a.y, b.z, acc[1][2]); acc[1][3] = fmaf(a.y, b.w, acc[1][3]);
        acc[2][0] = fmaf(a.z, b.x, acc[2][0]); acc[2][1] = fmaf(a.z, b.y, acc[2][1]);
        acc[2][2] = fmaf(a.z, b.z, acc[2][2]); acc[2][3] = fmaf(a.z, b.w, acc[2][3]);
        acc[3][0] = fmaf(a.w, b.x, acc[3][0]); acc[3][1] = fmaf(a.w, b.y, acc[3][1]);
        acc[3][2] = fmaf(a.w, b.z, acc[3][2]); acc[3][3] = fmaf(a.w, b.w, acc[3][3]);
    }

    float4 bc = *(const float4*)(b1 + (tx << 2));
#pragma unroll
    for (int i = 0; i < 4; i++) {
        float4 o;
        o.x = eluf(acc[i][0] + bc.x);
        o.y = eluf(acc[i][1] + bc.y);
        o.z = eluf(acc[i][2] + bc.z);
        o.w = eluf(acc[i][3] + bc.w);
        *(float4*)(out + (size_t)(p0 + (ty << 2) + i) * 32 + (tx << 2)) = o;
    }
}

// conv2/conv3: in [n][IS][IS][32] -> out [n+off][OS][OS][32], stride2 pad1, ELU
template<int IS, int OS>
__global__ __launch_bounds__(256) void convg_k(const float* __restrict__ in,
    const float* __restrict__ wtb, const float* __restrict__ bias,
    float* __restrict__ out, int pOff)
{
    __shared__ float Bs[288 * 32];
    __shared__ float As[32][132];
    int tid = threadIdx.x;
    {
        const float4* src = (const float4*)wtb;
        float4* dst = (float4*)Bs;
#pragma unroll
        for (int r = 0; r < 9; r++) dst[tid + r * 256] = src[tid + r * 256];
    }
    const int OS2 = OS * OS;
    int p0 = blockIdx.x << 7;
    int c4 = tid & 7;
    int pn[4], pox[4], poy[4];
#pragma unroll
    for (int i = 0; i < 4; i++) {
        int px = (tid >> 3) + (i << 5);
        int p = p0 + px;
        int n = p / OS2;
        int rem = p - n * OS2;
        int ox = rem / OS;
        pn[i] = n; pox[i] = ox; poy[i] = rem - ox * OS;
    }

    int tx = tid & 7, ty = tid >> 3;
    float acc[4][4];
#pragma unroll
    for (int i = 0; i < 4; i++)
#pragma unroll
        for (int j = 0; j < 4; j++) acc[i][j] = 0.f;

    for (int k1 = 0; k1 < 3; k1++) {
        for (int k2 = 0; k2 < 3; k2++) {
            __syncthreads();
#pragma unroll
            for (int i = 0; i < 4; i++) {
                int px = (tid >> 3) + (i << 5);
                int u = 2 * pox[i] - 1 + k1;
                int v = 2 * poy[i] - 1 + k2;
                bool ok = (u >= 0) && (u < IS) && (v >= 0) && (v < IS);
                int uc = ok ? u : 0, vc = ok ? v : 0;
                float4 val = *(const float4*)(in +
                    ((size_t)((pn[i] * IS + uc) * IS + vc)) * 32 + (c4 << 2));
                if (!ok) { val.x = 0.f; val.y = 0.f; val.z = 0.f; val.w = 0.f; }
                As[(c4 << 2) + 0][px] = val.x;
                As[(c4 << 2) + 1][px] = val.y;
                As[(c4 << 2) + 2][px] = val.z;
                As[(c4 << 2) + 3][px] = val.w;
            }
            __syncthreads();
            const float* bsrc = Bs + (size_t)((k1 * 3 + k2) << 5) * 32;
#pragma unroll 8
            for (int k = 0; k < 32; k++) {
                float4 a = *(const float4*)&As[k][ty << 2];
                float4 b = *(const float4*)&bsrc[(k << 5) + (tx << 2)];
                acc[0][0] = fmaf(a.x, b.x, acc[0][0]); acc[0][1] = fmaf(a.x, b.y, acc[0][1]);
                acc[0][2] = fmaf(a.x, b.z, acc[0][2]); acc[0][3] = fmaf(a.x, b.w, acc[0][3]);
                acc[1][0] = fmaf(a.y, b.x, acc[1][0]); acc[1][1] = fmaf(a.y, b.y, acc[1][1]);
                acc[1][2] = fmaf(a.y, b.z, acc[1][2]); acc[1][3] = fmaf(a.y, b.w, acc[1][3]);
                acc[2][0] = fmaf(a.z, b.x, acc[2][0]); acc[2][1] = fmaf(a.z, b.y, acc[2][1]);
                acc[2][2] = fmaf(a.z, b.z, acc[2][2]); acc[2][3] = fmaf(a.z, b.w, acc[2][3]);
                acc[3][0] = fmaf(a.w, b.x, acc[3][0]); acc[3][1] = fmaf(a.w, b.y, acc[3][1]);
                acc[3][2] = fmaf(a.w, b.z, acc[3][2]); acc[3][3] = fmaf(a.w, b.w, acc[3][3]);
            }
        }
    }

    float4 bc = *(const float4*)(bias + (tx << 2));
#pragma unroll
    for (int i = 0; i < 4; i++) {
        float4 o;
        o.x = eluf(acc[i][0] + bc.x);
        o.y = eluf(acc[i][1] + bc.y);
        o.z = eluf(acc[i][2] + bc.z);
        o.w = eluf(acc[i][3] + bc.w);
        *(float4*)(out + (size_t)(pOff + p0 + (ty << 2) + i) * 32 + (tx << 2)) = o;
    }
}

// fw1t[h][p*32+co] = fw1[h][co*121+p]  (match conv3 K-order)
__global__ __launch_bounds__(256) void repack_fw1(const float* __restrict__ fw1,
    float* __restrict__ fw1t)
{
    __shared__ float row[3872];
    int h = blockIdx.x;
    const float* src = fw1 + (size_t)h * 3872;
    for (int j = threadIdx.x; j < 3872; j += 256) row[j] = src[j];
    __syncthreads();
    float* dst = fw1t + (size_t)h * 3872;
    for (int j = threadIdx.x; j < 3872; j += 256) {
        int p = j >> 5, co = j & 31;
        dst[j] = row[co * 121 + p];
    }
}

// C[m,n] (+)= sum_k A[m*K+k] * Bm[n*K+k]
// 128x128 tile, 8x8/thread, dbuf LDS, 1 barrier/tile.
// NOTE: no min-occupancy hint — (256,4) clamped VGPRs to 64 and spilled acc
// to scratch (R2: 6.5 GB scratch traffic/dispatch, 10x regression).
__global__ __launch_bounds__(256) void gemm128(const float* __restrict__ A,
    const float* __restrict__ Bm, float* __restrict__ C,
    int M, int N, int K, int Nt, int kchunk, int splitk)
{
    __shared__ float As[2][16][132];
    __shared__ float Bs[2][16][132];
    int tid = threadIdx.x;
    int bid = blockIdx.x;
    int nt = bid % Nt, mt = bid / Nt;
    int n0 = nt << 7, m0 = mt << 7;
    int kbeg = blockIdx.z * kchunk;
    int kend = kbeg + kchunk;
    if (kend > K) kend = K;
    int T = (kend - kbeg) >> 4;

    int tx = tid & 15, ty = tid >> 4;
    // staging indices: 2 float4 each for A and B
    int r0 = tid >> 2, kc0 = (tid & 3) << 2;          // i = tid
    int r1 = (tid + 256) >> 2, kc1 = kc0;             // i = tid+256 (same kc)
    const float* a0p = A + (size_t)(m0 + r0) * K + kbeg + kc0;
    const float* a1p = A + (size_t)(m0 + r1) * K + kbeg + kc1;
    const float* b0p = Bm + (size_t)(n0 + r0) * K + kbeg + kc0;
    const float* b1p = Bm + (size_t)(n0 + r1) * K + kbeg + kc1;

    float acc[8][8];
#pragma unroll
    for (int i = 0; i < 8; i++)
#pragma unroll
        for (int j = 0; j < 8; j++) acc[i][j] = 0.f;

    float4 pa0 = *(const float4*)a0p;
    float4 pa1 = *(const float4*)a1p;
    float4 pb0 = *(const float4*)b0p;
    float4 pb1 = *(const float4*)b1p;
    As[0][kc0 + 0][r0] = pa0.x; As[0][kc0 + 1][r0] = pa0.y;
    As[0][kc0 + 2][r0] = pa0.z; As[0][kc0 + 3][r0] = pa0.w;
    As[0][kc1 + 0][r1] = pa1.x; As[0][kc1 + 1][r1] = pa1.y;
    As[0][kc1 + 2][r1] = pa1.z; As[0][kc1 + 3][r1] = pa1.w;
    Bs[0][kc0 + 0][r0] = pb0.x; Bs[0][kc0 + 1][r0] = pb0.y;
    Bs[0][kc0 + 2][r0] = pb0.z; Bs[0][kc0 + 3][r0] = pb0.w;
    Bs[0][kc1 + 0][r1] = pb1.x; Bs[0][kc1 + 1][r1] = pb1.y;
    Bs[0][kc1 + 2][r1] = pb1.z; Bs[0][kc1 + 3][r1] = pb1.w;

    int p = 0;
    for (int t = 0; t < T; t++) {
        __syncthreads();               // buf p valid; buf 1-p free
        bool more = (t + 1 < T);
        if (more) {
            int ko = (t + 1) << 4;
            pa0 = *(const float4*)(a0p + ko);
            pa1 = *(const float4*)(a1p + ko);
            pb0 = *(const float4*)(b0p + ko);
            pb1 = *(const float4*)(b1p + ko);
        }
#pragma unroll
        for (int k = 0; k < 16; k++) {
            float a[8], b[8];
            *(float4*)&a[0] = *(const float4*)&As[p][k][ty << 2];
            *(float4*)&a[4] = *(const float4*)&As[p][k][64 + (ty << 2)];
            *(float4*)&b[0] = *(const float4*)&Bs[p][k][tx << 2];
            *(float4*)&b[4] = *(const float4*)&Bs[p][k][64 + (tx << 2)];
#pragma unroll
            for (int i = 0; i < 8; i++)
#pragma unroll
                for (int j = 0; j < 8; j++) acc[i][j] = fmaf(a[i], b[j], acc[i][j]);
        }
        if (more) {
            int q = p ^ 1;
            As[q][kc0 + 0][r0] = pa0.x; As[q][kc0 + 1][r0] = pa0.y;
            As[q][kc0 + 2][r0] = pa0.z; As[q][kc0 + 3][r0] = pa0.w;
            As[q][kc1 + 0][r1] = pa1.x; As[q][kc1 + 1][r1] = pa1.y;
            As[q][kc1 + 2][r1] = pa1.z; As[q][kc1 + 3][r1] = pa1.w;
            Bs[q][kc0 + 0][r0] = pb0.x; Bs[q][kc0 + 1][r0] = pb0.y;
            Bs[q][kc0 + 2][r0] = pb0.z; Bs[q][kc0 + 3][r0] = pb0.w;
            Bs[q][kc1 + 0][r1] = pb1.x; Bs[q][kc1 + 1][r1] = pb1.y;
            Bs[q][kc1 + 2][r1] = pb1.z; Bs[q][kc1 + 3][r1] = pb1.w;
            p = q;
        }
    }

#pragma unroll
    for (int i = 0; i < 8; i++) {
        int row = m0 + ((i < 4) ? ((ty << 2) + i) : (64 + (ty << 2) + i - 4));
        float* cp0 = C + (size_t)row * N + n0 + (tx << 2);
        float* cp1 = cp0 + 64;
        if (splitk > 1) {
            atomicAdd(cp0 + 0, acc[i][0]); atomicAdd(cp0 + 1, acc[i][1]);
            atomicAdd(cp0 + 2, acc[i][2]); atomicAdd(cp0 + 3, acc[i][3]);
            atomicAdd(cp1 + 0, acc[i][4]); atomicAdd(cp1 + 1, acc[i][5]);
            atomicAdd(cp1 + 2, acc[i][6]); atomicAdd(cp1 + 3, acc[i][7]);
        } else {
            float4 s0; s0.x = acc[i][0]; s0.y = acc[i][1]; s0.z = acc[i][2]; s0.w = acc[i][3];
            float4 s1; s1.x = acc[i][4]; s1.y = acc[i][5]; s1.z = acc[i][6]; s1.w = acc[i][7];
            *(float4*)cp0 = s0;
            *(float4*)cp1 = s1;
        }
    }
}

__global__ __launch_bounds__(256) void bias_relu(float* __restrict__ x,
    const float* __restrict__ b, int total)
{
    int i = blockIdx.x * 256 + threadIdx.x;
    if (i < total) {
        float v = x[i] + b[i & 1023];
        x[i] = v > 0.f ? v : 0.f;
    }
}

// one LSTM step for one layer. grid 512: bid = jblk*2 + bbhalf
// block: bl=tid&15 (row), q=(tid>>4)&3 (unit of 4), s=tid>>6 (k-quarter)
__global__ __launch_bounds__(256) void lstm_step(
    const float* __restrict__ gx,      // [1024][4096] rows t*32+b
    const float* __restrict__ whh,     // [4096][1024]
    const float* __restrict__ bsum,    // [4096]
    const float* __restrict__ hprev,   // rows b*1024 (pre-offset for t/layer)
    const float* __restrict__ cprev,   // idx b*1024+j (pre-offset for layer)
    float* __restrict__ cout,          // idx b*1024+j
    float* __restrict__ Hout,          // rows t*32+b
    const unsigned char* __restrict__ dmask, // &done[t*32] as bytes
    int t)
{
    __shared__ float Hs[16][260];
    __shared__ float part[3][64][4];
    int tid = threadIdx.x;
    int jblk = blockIdx.x >> 1;
    int bb = (blockIdx.x & 1) << 4;
    int bl = tid & 15;
    int q  = (tid >> 4) & 3;
    int s  = tid >> 6;
    int j = (jblk << 2) + q;
    const float* wi = whh + (size_t)j * 1024;
    const float* wf = wi + (size_t)1024 * 1024;
    const float* wg = wf + (size_t)1024 * 1024;
    const float* wo = wg + (size_t)1024 * 1024;
    float a0 = 0.f, a1 = 0.f, a2 = 0.f, a3 = 0.f;

    for (int kt = 0; kt < 4; kt++) {
        if (kt) __syncthreads();
#pragma unroll
        for (int rep = 0; rep < 4; rep++) {
            int id = tid + (rep << 8);
            int r = id >> 6;
            int c4 = id & 63;
            float4 h4 = *(const float4*)(hprev + (size_t)(bb + r) * 1024 + (kt << 8) + (c4 << 2));
            float nd = dmask[bb + r] ? 0.f : 1.f;
            h4.x *= nd; h4.y *= nd; h4.z *= nd; h4.w *= nd;
            *(float4*)&Hs[r][c4 << 2] = h4;
        }
        __syncthreads();
#pragma unroll
        for (int kq = 0; kq < 16; kq++) {
            int kl = (s << 6) + (kq << 2);
            float4 h4 = *(const float4*)&Hs[bl][kl];
            int kG = (kt << 8) + kl;
            float4 w0 = *(const float4*)(wi + kG);
            float4 w1 = *(const float4*)(wf + kG);
            float4 w2 = *(const float4*)(wg + kG);
            float4 w3 = *(const float4*)(wo + kG);
            a0 = fmaf(h4.x, w0.x, fmaf(h4.y, w0.y, fmaf(h4.z, w0.z, fmaf(h4.w, w0.w, a0))));
            a1 = fmaf(h4.x, w1.x, fmaf(h4.y, w1.y, fmaf(h4.z, w1.z, fmaf(h4.w, w1.w, a1))));
            a2 = fmaf(h4.x, w2.x, fmaf(h4.y, w2.y, fmaf(h4.z, w2.z, fmaf(h4.w, w2.w, a2))));
            a3 = fmaf(h4.x, w3.x, fmaf(h4.y, w3.y, fmaf(h4.z, w3.z, fmaf(h4.w, w3.w, a3))));
        }
    }
    if (s) {
        float4 pv; pv.x = a0; pv.y = a1; pv.z = a2; pv.w = a3;
        *(float4*)&part[s - 1][tid & 63][0] = pv;
    }
    __syncthreads();
    if (!s) {
#pragma unroll
        for (int r = 0; r < 3; r++) {
            float4 pv = *(const float4*)&part[r][tid][0];
            a0 += pv.x; a1 += pv.y; a2 += pv.z; a3 += pv.w;
        }
        int b = bb + bl;
        int row = (t << 5) + b;
        const float* gp = gx + (size_t)row * 4096 + j;
        float g0 = a0 + gp[0]    + bsum[j];
        float g1 = a1 + gp[1024] + bsum[j + 1024];
        float g2 = a2 + gp[2048] + bsum[j + 2048];
        float g3 = a3 + gp[3072] + bsum[j + 3072];
        float nd = dmask[b] ? 0.f : 1.f;
        float cp = cprev[(size_t)b * 1024 + j] * nd;
        float si = 1.f / (1.f + expf(-g0));
        float sf = 1.f / (1.f + expf(-g1));
        float so = 1.f / (1.f + expf(-g3));
        float cn = sf * cp + si * tanhf(g2);
        float hn = so * tanhf(cn);
        cout[(size_t)b * 1024 + j] = cn;
        Hout[(size_t)row * 1024 + j] = hn;
    }
}

__global__ __launch_bounds__(256) void heads_k(const float* __restrict__ Hc,
    const float* __restrict__ pw, const float* __restrict__ pb,
    const float* __restrict__ bw, const float* __restrict__ bbias,
    float* __restrict__ out)
{
    __shared__ float red[8][264];
    int n = blockIdx.x, tid = threadIdx.x;
    float4 x4 = *(const float4*)(Hc + (size_t)n * 1024 + (tid << 2));
#pragma unroll
    for (int a = 0; a < 7; a++) {
        float4 w4 = *(const float4*)(pw + (size_t)a * 1024 + (tid << 2));
        red[a][tid] = x4.x * w4.x + x4.y * w4.y + x4.z * w4.z + x4.w * w4.w;
    }
    {
        float4 w4 = *(const float4*)(bw + (tid << 2));
        red[7][tid] = x4.x * w4.x + x4.y * w4.y + x4.z * w4.z + x4.w * w4.w;
    }
    __syncthreads();
    for (int off = 128; off > 0; off >>= 1) {
        if (tid < off) {
#pragma unroll
            for (int a = 0; a < 8; a++) red[a][tid] += red[a][tid + off];
        }
        __syncthreads();
    }
    if (tid == 0) {
        float best = -1e30f; int bi = 0;
        for (int a = 0; a < 7; a++) {
            float L = red[a][0] + pb[a];
            out[n * 7 + a] = L;
            if (L > best) { best = L; bi = a; }
        }
        out[7168 + n] = red[7][0] + bbias[0];
        out[8192 + n] = (float)bi;
    }
}

__global__ __launch_bounds__(256) void final_copy(const float* __restrict__ H0,
    const float* __restrict__ H1, const float* __restrict__ cst, float* __restrict__ out)
{
    int i = blockIdx.x * 256 + threadIdx.x;   // 131072 exact
    if (i < 65536) {
        int l = i >> 15;
        int rem = i & 32767;
        const float* H = l ? H1 : H0;
        out[9216 + i] = H[(size_t)(31 * 32) * 1024 + rem];
    } else {
        out[74752 + (i - 65536)] = cst[i - 65536];
    }
}

extern "C" void kernel_launch(void* const* d_in, const int* in_sizes, int n_in,
                              void* d_out, int out_size, void* d_ws, size_t ws_size,
                              hipStream_t stream)
{
    (void)in_sizes; (void)n_in; (void)out_size; (void)ws_size;
    const float* frame = (const float*)d_in[0];
    const unsigned char* done8 = (const unsigned char*)d_in[1];
    const float* h0   = (const float*)d_in[2];
    const float* c0   = (const float*)d_in[3];
    const float* cw1  = (const float*)d_in[4];
    const float* cb1  = (const float*)d_in[5];
    const float* cw2  = (const float*)d_in[6];
    const float* cb2  = (const float*)d_in[7];
    const float* cw3  = (const float*)d_in[8];
    const float* cb3  = (const float*)d_in[9];
    const float* fw1  = (const float*)d_in[10];
    const float* fb1  = (const float*)d_in[11];
    const float* fw2  = (const float*)d_in[12];
    const float* fb2  = (const float*)d_in[13];
    const float* wih0 = (const float*)d_in[14];
    const float* whh0 = (const float*)d_in[15];
    const float* bih0 = (const float*)d_in[16];
    const float* bhh0 = (const float*)d_in[17];
    const float* wih1 = (const float*)d_in[18];
    const float* whh1 = (const float*)d_in[19];
    const float* bih1 = (const float*)d_in[20];
    const float* bhh1 = (const float*)d_in[21];
    const float* pw   = (const float*)d_in[22];
    const float* pb   = (const float*)d_in[23];
    const float* bw   = (const float*)d_in[24];
    const float* bbias= (const float*)d_in[25];

    float* ws   = (float*)d_ws;
    float* A    = ws;                      // 14,450,688
    float* Bv   = A + 14450688;            //  7,225,344
    float* fc1  = Bv + 7225344;            //  1,048,576
    float* cin  = fc1 + 1048576;           //  1,048,576
    float* H0   = cin + 1048576;           //  1,048,576
    float* H1   = H0 + 1048576;            //  1,048,576
    float* cst  = H1 + 1048576;            //     65,536
    float* bsum = cst + 65536;             //      8,192
    float* wt   = bsum + 8192;             //     19,296
    float* gx0 = A;
    float* gx1 = A + 4194304;
    float* fw1t = A + 8388608;             //  3,964,928 (dead conv2 space)
    float* conv2f = A;
    float* conv3o = Bv;
    float* out = (float*)d_out;

    repack_w<<<76, 256, 0, stream>>>(cw1, cw2, cw3, wt);
    bsum_k<<<32, 256, 0, stream>>>(bih0, bhh0, bih1, bhh1, bsum);

    for (int ch = 0; ch < 8; ch++) {
        conv1_k<<<1764, 256, 0, stream>>>(frame, wt, cb1, Bv, ch * 128);
        convg_k<42, 21><<<441, 256, 0, stream>>>(Bv, wt + 864, cb2, conv2f, ch * 128 * 441);
    }
    convg_k<21, 11><<<968, 256, 0, stream>>>(conv2f, wt + 10080, cb3, conv3o, 0);
    repack_fw1<<<1024, 256, 0, stream>>>(fw1, fw1t);

    hipMemsetAsync(fc1, 0, (size_t)1048576 * 4, stream);
    hipMemsetAsync(cin, 0, (size_t)1048576 * 4, stream);
    // FC1: M=1024 N=1024 K=3872, Nt=8 -> grid 64 x splitk4 (kchunk 976 mult of 16)
    { dim3 g(64, 1, 4); gemm128<<<g, 256, 0, stream>>>(conv3o, fw1t, fc1, 1024, 1024, 3872, 8, 976, 4); }
    bias_relu<<<4096, 256, 0, stream>>>(fc1, fb1, 1048576);
    { dim3 g(64, 1, 2); gemm128<<<g, 256, 0, stream>>>(fc1, fw2, cin, 1024, 1024, 1024, 8, 512, 2); }
    bias_relu<<<4096, 256, 0, stream>>>(cin, fb2, 1048576);

    // gx: M=1024 N=4096 K=1024, Nt=32 -> grid 256, no splitk
    { dim3 g(256, 1, 1); gemm128<<<g, 256, 0, stream>>>(cin, wih0, gx0, 1024, 4096, 1024, 32, 1024, 1); }
    for (int t = 0; t < 32; t++) {
        const float* hp = t ? (H0 + (size_t)(t - 1) * 32768) : h0;
        const float* cp = t ? cst : c0;
        lstm_step<<<512, 256, 0, stream>>>(gx0, whh0, bsum, hp, cp, cst, H0, done8 + t * 32, t);
    }
    { dim3 g(256, 1, 1); gemm128<<<g, 256, 0, stream>>>(H0, wih1, gx1, 1024, 4096, 1024, 32, 1024, 1); }
    for (int t = 0; t < 32; t++) {
        const float* hp = t ? (H1 + (size_t)(t - 1) * 32768) : (h0 + 32768);
        const float* cp = t ? (cst + 32768) : (c0 + 32768);
        lstm_step<<<512, 256, 0, stream>>>(gx1, whh1, bsum + 4096, hp, cp, cst + 32768, H1, done8 + t * 32, t);
    }
    heads_k<<<1024, 256, 0, stream>>>(H1, pw, pb, bw, bbias, out);
    final_copy<<<512, 256, 0, stream>>>(H0, H1, cst, out);
}

// Round 5
// 2538.634 us; speedup vs baseline: 2.9192x; 1.0450x over previous
//
#include <hip/hip_runtime.h>
#include <cmath>

// ---------------- problem constants ----------------
// T=32 B=32 H=W=84 C=3 HID=1024, conv: 84->42->21->11, CONV_OUT=3872
// outputs: logits[1024*7] | baseline[1024] | action[1024] | h_fin[65536] | c_fin[65536]
// activation layouts: conv1 out [n][42][42][32], conv2 out [n][21][21][32],
// conv3 out [n][11][11][32] (=[n][p][co], K-order p*32+co; fc_w1 repacked to match)

// ---------------- ws layout (floats) ----------------
// A      : 14,450,688  conv2 full [1024][21][21][32]; then FC partials @A+0 (<=8.39M),
//                      fw1t @A+8388608 (3.96M); then gx partials @A+0 and @A+4194304
// Bv     :  7,225,344  conv1 chunk [128][42][42][32]; later conv3out [1024][3872]
// fc1    :  1,048,576
// cin    :  1,048,576
// H0     :  1,048,576
// H1     :  1,048,576
// cst    :     65,536
// bsum   :      8,192
// wt     :     19,296

__device__ __forceinline__ float eluf(float v) {
    return v > 0.f ? v : expm1f(v);
}

// weights repacked k-major: wt[(tap*CI+ci)*32 + co]
__global__ __launch_bounds__(256) void repack_w(const float* __restrict__ w1,
    const float* __restrict__ w2, const float* __restrict__ w3, float* __restrict__ wt)
{
    int i = blockIdx.x * 256 + threadIdx.x;
    if (i < 864) {
        int co = i & 31, r = i >> 5;
        int tap = r / 3, ci = r - tap * 3;
        int k1 = tap / 3, k2 = tap - k1 * 3;
        wt[i] = w1[co * 27 + ci * 9 + k1 * 3 + k2];
    } else if (i < 10080) {
        int o = i - 864;
        int co = o & 31, r = o >> 5;
        int tap = r >> 5, ci = r & 31;
        int k1 = tap / 3, k2 = tap - k1 * 3;
        wt[i] = w2[co * 288 + ci * 9 + k1 * 3 + k2];
    } else if (i < 19296) {
        int o = i - 10080;
        int co = o & 31, r = o >> 5;
        int tap = r >> 5, ci = r & 31;
        int k1 = tap / 3, k2 = tap - k1 * 3;
        wt[i] = w3[co * 288 + ci * 9 + k1 * 3 + k2];
    }
}

__global__ __launch_bounds__(256) void bsum_k(const float* __restrict__ bih0,
    const float* __restrict__ bhh0, const float* __restrict__ bih1,
    const float* __restrict__ bhh1, float* __restrict__ bsum)
{
    int i = blockIdx.x * 256 + threadIdx.x;
    if (i < 4096) bsum[i] = bih0[i] + bhh0[i];
    else if (i < 8192) bsum[i] = bih1[i - 4096] + bhh1[i - 4096];
}

// conv1: frame [n][h][w][3] -> out [nl][ox][oy][32], 42x42, stride2 pad1, ELU
__global__ __launch_bounds__(256) void conv1_k(const float* __restrict__ frame,
    const float* __restrict__ w1t, const float* __restrict__ b1,
    float* __restrict__ out, int n0)
{
    __shared__ float As[27][132];
    __shared__ float Bs[27][32];
    int tid = threadIdx.x;
    if (tid < 216) ((float4*)Bs)[tid] = ((const float4*)w1t)[tid];

    int p0 = blockIdx.x << 7;
    int pxl = tid & 127;
    int half = tid >> 7;
    {
        int p = p0 + pxl;
        int nl = p / 1764;
        int rem = p - nl * 1764;
        int ox = rem / 42;
        int oy = rem - ox * 42;
        const float* fr = frame + (size_t)(n0 + nl) * 21168;
        for (int tap = half; tap < 9; tap += 2) {
            int k1 = tap / 3, k2 = tap - k1 * 3;
            int u = 2 * ox - 1 + k1;
            int v = 2 * oy - 1 + k2;
            bool ok = (u >= 0) && (u < 84) && (v >= 0) && (v < 84);
            int uc = ok ? u : 0, vc = ok ? v : 0;
            const float* fp = fr + (vc * 84 + uc) * 3;
            float x0 = fp[0], x1 = fp[1], x2 = fp[2];
            if (!ok) { x0 = 0.f; x1 = 0.f; x2 = 0.f; }
            As[tap * 3 + 0][pxl] = x0;
            As[tap * 3 + 1][pxl] = x1;
            As[tap * 3 + 2][pxl] = x2;
        }
    }
    __syncthreads();

    int tx = tid & 7, ty = tid >> 3;
    float acc[4][4];
#pragma unroll
    for (int i = 0; i < 4; i++)
#pragma unroll
        for (int j = 0; j < 4; j++) acc[i][j] = 0.f;

#pragma unroll 9
    for (int k = 0; k < 27; k++) {
        float4 a = *(const float4*)&As[k][ty << 2];
        float4 b = *(const float4*)&Bs[k][tx << 2];
        acc[0][0] = fmaf(a.x, b.x, acc[0][0]); acc[0][1] = fmaf(a.x, b.y, acc[0][1]);
        acc[0][2] = fmaf(a.x, b.z, acc[0][2]); acc[0][3] = fmaf(a.x, b.w, acc[0][3]);
        acc[1][0] = fmaf(a.y, b.x, acc[1][0]); acc[1][1] = fmaf(a.y, b.y, acc[1][1]);
        acc[1][2] = fmaf(a.y, b.z, acc[1][2]); acc[1][3] = fmaf(a.y, b.w, acc[1][3]);
        acc[2][0] = fmaf(a.z, b.x, acc[2][0]); acc[2][1] = fmaf(a.z, b.y, acc[2][1]);
        acc[2][2] = fmaf(a.z, b.z, acc[2][2]); acc[2][3] = fmaf(a.z, b.w, acc[2][3]);
        acc[3][0] = fmaf(a.w, b.x, acc[3][0]); acc[3][1] = fmaf(a.w, b.y, acc[3][1]);
        acc[3][2] = fmaf(a.w, b.z, acc[3][2]); acc[3][3] = fmaf(a.w, b.w, acc[3][3]);
    }

    float4 bc = *(const float4*)(b1 + (tx << 2));
#pragma unroll
    for (int i = 0; i < 4; i++) {
        float4 o;
        o.x = eluf(acc[i][0] + bc.x);
        o.y = eluf(acc[i][1] + bc.y);
        o.z = eluf(acc[i][2] + bc.z);
        o.w = eluf(acc[i][3] + bc.w);
        *(float4*)(out + (size_t)(p0 + (ty << 2) + i) * 32 + (tx << 2)) = o;
    }
}

// conv2/conv3: in [n][IS][IS][32] -> out [n+off][OS][OS][32], stride2 pad1, ELU
template<int IS, int OS>
__global__ __launch_bounds__(256) void convg_k(const float* __restrict__ in,
    const float* __restrict__ wtb, const float* __restrict__ bias,
    float* __restrict__ out, int pOff)
{
    __shared__ float Bs[288 * 32];
    __shared__ float As[32][132];
    int tid = threadIdx.x;
    {
        const float4* src = (const float4*)wtb;
        float4* dst = (float4*)Bs;
#pragma unroll
        for (int r = 0; r < 9; r++) dst[tid + r * 256] = src[tid + r * 256];
    }
    const int OS2 = OS * OS;
    int p0 = blockIdx.x << 7;
    int c4 = tid & 7;
    int pn[4], pox[4], poy[4];
#pragma unroll
    for (int i = 0; i < 4; i++) {
        int px = (tid >> 3) + (i << 5);
        int p = p0 + px;
        int n = p / OS2;
        int rem = p - n * OS2;
        int ox = rem / OS;
        pn[i] = n; pox[i] = ox; poy[i] = rem - ox * OS;
    }

    int tx = tid & 7, ty = tid >> 3;
    float acc[4][4];
#pragma unroll
    for (int i = 0; i < 4; i++)
#pragma unroll
        for (int j = 0; j < 4; j++) acc[i][j] = 0.f;

    for (int k1 = 0; k1 < 3; k1++) {
        for (int k2 = 0; k2 < 3; k2++) {
            __syncthreads();
#pragma unroll
            for (int i = 0; i < 4; i++) {
                int px = (tid >> 3) + (i << 5);
                int u = 2 * pox[i] - 1 + k1;
                int v = 2 * poy[i] - 1 + k2;
                bool ok = (u >= 0) && (u < IS) && (v >= 0) && (v < IS);
                int uc = ok ? u : 0, vc = ok ? v : 0;
                float4 val = *(const float4*)(in +
                    ((size_t)((pn[i] * IS + uc) * IS + vc)) * 32 + (c4 << 2));
                if (!ok) { val.x = 0.f; val.y = 0.f; val.z = 0.f; val.w = 0.f; }
                As[(c4 << 2) + 0][px] = val.x;
                As[(c4 << 2) + 1][px] = val.y;
                As[(c4 << 2) + 2][px] = val.z;
                As[(c4 << 2) + 3][px] = val.w;
            }
            __syncthreads();
            const float* bsrc = Bs + (size_t)((k1 * 3 + k2) << 5) * 32;
#pragma unroll 8
            for (int k = 0; k < 32; k++) {
                float4 a = *(const float4*)&As[k][ty << 2];
                float4 b = *(const float4*)&bsrc[(k << 5) + (tx << 2)];
                acc[0][0] = fmaf(a.x, b.x, acc[0][0]); acc[0][1] = fmaf(a.x, b.y, acc[0][1]);
                acc[0][2] = fmaf(a.x, b.z, acc[0][2]); acc[0][3] = fmaf(a.x, b.w, acc[0][3]);
                acc[1][0] = fmaf(a.y, b.x, acc[1][0]); acc[1][1] = fmaf(a.y, b.y, acc[1][1]);
                acc[1][2] = fmaf(a.y, b.z, acc[1][2]); acc[1][3] = fmaf(a.y, b.w, acc[1][3]);
                acc[2][0] = fmaf(a.z, b.x, acc[2][0]); acc[2][1] = fmaf(a.z, b.y, acc[2][1]);
                acc[2][2] = fmaf(a.z, b.z, acc[2][2]); acc[2][3] = fmaf(a.z, b.w, acc[2][3]);
                acc[3][0] = fmaf(a.w, b.x, acc[3][0]); acc[3][1] = fmaf(a.w, b.y, acc[3][1]);
                acc[3][2] = fmaf(a.w, b.z, acc[3][2]); acc[3][3] = fmaf(a.w, b.w, acc[3][3]);
            }
        }
    }

    float4 bc = *(const float4*)(bias + (tx << 2));
#pragma unroll
    for (int i = 0; i < 4; i++) {
        float4 o;
        o.x = eluf(acc[i][0] + bc.x);
        o.y = eluf(acc[i][1] + bc.y);
        o.z = eluf(acc[i][2] + bc.z);
        o.w = eluf(acc[i][3] + bc.w);
        *(float4*)(out + (size_t)(pOff + p0 + (ty << 2) + i) * 32 + (tx << 2)) = o;
    }
}

// fw1t[h][p*32+co] = fw1[h][co*121+p]  (match conv3 K-order)
__global__ __launch_bounds__(256) void repack_fw1(const float* __restrict__ fw1,
    float* __restrict__ fw1t)
{
    __shared__ float row[3872];
    int h = blockIdx.x;
    const float* src = fw1 + (size_t)h * 3872;
    for (int j = threadIdx.x; j < 3872; j += 256) row[j] = src[j];
    __syncthreads();
    float* dst = fw1t + (size_t)h * 3872;
    for (int j = threadIdx.x; j < 3872; j += 256) {
        int p = j >> 5, co = j & 31;
        dst[j] = row[co * 121 + p];
    }
}

// C[m,n] = sum_k A[m*K+k] * Bm[n*K+k] over this z's K-chunk.
// 128x128 tile, 8x8/thread, dbuf LDS. Partial output per z:
// C = Cbase + z*Cstride (no atomics; consumer sums partials).
__global__ __launch_bounds__(256) void gemm128(const float* __restrict__ A,
    const float* __restrict__ Bm, float* __restrict__ Cbase, size_t Cstride,
    int N, int K, int Nt, int kchunk)
{
    __shared__ float As[2][16][132];
    __shared__ float Bs[2][16][132];
    int tid = threadIdx.x;
    int bid = blockIdx.x;
    int nt = bid % Nt, mt = bid / Nt;
    int n0 = nt << 7, m0 = mt << 7;
    int kbeg = blockIdx.z * kchunk;
    int kend = kbeg + kchunk;
    if (kend > K) kend = K;
    int T = (kend - kbeg) >> 4;
    float* C = Cbase + (size_t)blockIdx.z * Cstride;

    int tx = tid & 15, ty = tid >> 4;
    int r0 = tid >> 2, kc0 = (tid & 3) << 2;
    int r1 = (tid + 256) >> 2, kc1 = kc0;
    const float* a0p = A + (size_t)(m0 + r0) * K + kbeg + kc0;
    const float* a1p = A + (size_t)(m0 + r1) * K + kbeg + kc1;
    const float* b0p = Bm + (size_t)(n0 + r0) * K + kbeg + kc0;
    const float* b1p = Bm + (size_t)(n0 + r1) * K + kbeg + kc1;

    float acc[8][8];
#pragma unroll
    for (int i = 0; i < 8; i++)
#pragma unroll
        for (int j = 0; j < 8; j++) acc[i][j] = 0.f;

    float4 pa0 = *(const float4*)a0p;
    float4 pa1 = *(const float4*)a1p;
    float4 pb0 = *(const float4*)b0p;
    float4 pb1 = *(const float4*)b1p;
    As[0][kc0 + 0][r0] = pa0.x; As[0][kc0 + 1][r0] = pa0.y;
    As[0][kc0 + 2][r0] = pa0.z; As[0][kc0 + 3][r0] = pa0.w;
    As[0][kc1 + 0][r1] = pa1.x; As[0][kc1 + 1][r1] = pa1.y;
    As[0][kc1 + 2][r1] = pa1.z; As[0][kc1 + 3][r1] = pa1.w;
    Bs[0][kc0 + 0][r0] = pb0.x; Bs[0][kc0 + 1][r0] = pb0.y;
    Bs[0][kc0 + 2][r0] = pb0.z; Bs[0][kc0 + 3][r0] = pb0.w;
    Bs[0][kc1 + 0][r1] = pb1.x; Bs[0][kc1 + 1][r1] = pb1.y;
    Bs[0][kc1 + 2][r1] = pb1.z; Bs[0][kc1 + 3][r1] = pb1.w;

    int p = 0;
    for (int t = 0; t < T; t++) {
        __syncthreads();
        bool more = (t + 1 < T);
        if (more) {
            int ko = (t + 1) << 4;
            pa0 = *(const float4*)(a0p + ko);
            pa1 = *(const float4*)(a1p + ko);
            pb0 = *(const float4*)(b0p + ko);
            pb1 = *(const float4*)(b1p + ko);
        }
#pragma unroll
        for (int k = 0; k < 16; k++) {
            float a[8], b[8];
            *(float4*)&a[0] = *(const float4*)&As[p][k][ty << 2];
            *(float4*)&a[4] = *(const float4*)&As[p][k][64 + (ty << 2)];
            *(float4*)&b[0] = *(const float4*)&Bs[p][k][tx << 2];
            *(float4*)&b[4] = *(const float4*)&Bs[p][k][64 + (tx << 2)];
#pragma unroll
            for (int i = 0; i < 8; i++)
#pragma unroll
                for (int j = 0; j < 8; j++) acc[i][j] = fmaf(a[i], b[j], acc[i][j]);
        }
        if (more) {
            int q = p ^ 1;
            As[q][kc0 + 0][r0] = pa0.x; As[q][kc0 + 1][r0] = pa0.y;
            As[q][kc0 + 2][r0] = pa0.z; As[q][kc0 + 3][r0] = pa0.w;
            As[q][kc1 + 0][r1] = pa1.x; As[q][kc1 + 1][r1] = pa1.y;
            As[q][kc1 + 2][r1] = pa1.z; As[q][kc1 + 3][r1] = pa1.w;
            Bs[q][kc0 + 0][r0] = pb0.x; Bs[q][kc0 + 1][r0] = pb0.y;
            Bs[q][kc0 + 2][r0] = pb0.z; Bs[q][kc0 + 3][r0] = pb0.w;
            Bs[q][kc1 + 0][r1] = pb1.x; Bs[q][kc1 + 1][r1] = pb1.y;
            Bs[q][kc1 + 2][r1] = pb1.z; Bs[q][kc1 + 3][r1] = pb1.w;
            p = q;
        }
    }

#pragma unroll
    for (int i = 0; i < 8; i++) {
        int row = m0 + ((i < 4) ? ((ty << 2) + i) : (64 + (ty << 2) + i - 4));
        float* cp0 = C + (size_t)row * N + n0 + (tx << 2);
        float4 s0; s0.x = acc[i][0]; s0.y = acc[i][1]; s0.z = acc[i][2]; s0.w = acc[i][3];
        float4 s1; s1.x = acc[i][4]; s1.y = acc[i][5]; s1.z = acc[i][6]; s1.w = acc[i][7];
        *(float4*)cp0 = s0;
        *(float4*)(cp0 + 64) = s1;
    }
}

// out[i] = relu(bias[i%1024] + sum_z p[i + z*stride]) over 1048576 elements
__global__ __launch_bounds__(256) void bias_relu_sum(const float* __restrict__ p,
    size_t stride, int nz, const float* __restrict__ b, float* __restrict__ out)
{
    int i = blockIdx.x * 256 + threadIdx.x;
    float v = b[i & 1023];
    for (int z = 0; z < nz; z++) v += p[i + (size_t)z * stride];
    out[i] = v > 0.f ? v : 0.f;
}

// one LSTM step for one layer. grid 512 blocks = 512 unit-pairs.
// block: 2 units x 32 batch rows; thread: bl=tid&31 (b), q=(tid>>5)&1 (unit),
// s=tid>>6 (k-quarter, 256 k each). gx pre-activation = gxa + gxb (split-K partials).
__global__ __launch_bounds__(256) void lstm_step(
    const float* __restrict__ gxa,     // partial [1024][4096] rows t*32+b
    const float* __restrict__ gxb,     // partial
    const float* __restrict__ whh,     // [4096][1024]
    const float* __restrict__ bsum,    // [4096]
    const float* __restrict__ hprev,   // rows b*1024 (pre-offset for t/layer)
    const float* __restrict__ cprev,   // idx b*1024+j (pre-offset for layer)
    float* __restrict__ cout,          // idx b*1024+j
    float* __restrict__ Hout,          // rows t*32+b
    const unsigned char* __restrict__ dmask, // &done[t*32]
    int t)
{
    __shared__ float Hs[32][260];
    __shared__ float part[3][64][4];
    int tid = threadIdx.x;
    int bl = tid & 31;
    int q  = (tid >> 5) & 1;
    int s  = tid >> 6;
    int j = (blockIdx.x << 1) + q;
    const float* wi = whh + (size_t)j * 1024;
    const float* wf = wi + (size_t)1024 * 1024;
    const float* wg = wf + (size_t)1024 * 1024;
    const float* wo = wg + (size_t)1024 * 1024;
    float a0 = 0.f, a1 = 0.f, a2 = 0.f, a3 = 0.f;

    for (int kt = 0; kt < 4; kt++) {
        if (kt) __syncthreads();
        // stage h[32 rows][256 cols] for col range [kt*256, kt*256+256)
#pragma unroll
        for (int rep = 0; rep < 8; rep++) {
            int id = tid + (rep << 8);          // 0..2047 float4 slots
            int r = id >> 6;                    // 0..31
            int c4 = id & 63;                   // 0..63
            float4 h4 = *(const float4*)(hprev + (size_t)r * 1024 + (kt << 8) + (c4 << 2));
            float nd = dmask[r] ? 0.f : 1.f;
            h4.x *= nd; h4.y *= nd; h4.z *= nd; h4.w *= nd;
            *(float4*)&Hs[r][c4 << 2] = h4;
        }
        __syncthreads();
        // this thread's k-slice within kt: [s*64, s*64+64) -> 16 float4 per gate
#pragma unroll
        for (int kq = 0; kq < 16; kq++) {
            int kl = (s << 6) + (kq << 2);
            float4 h4 = *(const float4*)&Hs[bl][kl];
            int kG = (kt << 8) + kl;
            float4 w0 = *(const float4*)(wi + kG);
            float4 w1 = *(const float4*)(wf + kG);
            float4 w2 = *(const float4*)(wg + kG);
            float4 w3 = *(const float4*)(wo + kG);
            a0 = fmaf(h4.x, w0.x, fmaf(h4.y, w0.y, fmaf(h4.z, w0.z, fmaf(h4.w, w0.w, a0))));
            a1 = fmaf(h4.x, w1.x, fmaf(h4.y, w1.y, fmaf(h4.z, w1.z, fmaf(h4.w, w1.w, a1))));
            a2 = fmaf(h4.x, w2.x, fmaf(h4.y, w2.y, fmaf(h4.z, w2.z, fmaf(h4.w, w2.w, a2))));
            a3 = fmaf(h4.x, w3.x, fmaf(h4.y, w3.y, fmaf(h4.z, w3.z, fmaf(h4.w, w3.w, a3))));
        }
    }
    if (s) {
        float4 pv; pv.x = a0; pv.y = a1; pv.z = a2; pv.w = a3;
        *(float4*)&part[s - 1][tid & 63][0] = pv;
    }
    __syncthreads();
    if (!s) {
#pragma unroll
        for (int r = 0; r < 3; r++) {
            float4 pv = *(const float4*)&part[r][tid][0];
            a0 += pv.x; a1 += pv.y; a2 += pv.z; a3 += pv.w;
        }
        int b = bl;
        int row = (t << 5) + b;
        const float* gpa = gxa + (size_t)row * 4096 + j;
        const float* gpb = gxb + (size_t)row * 4096 + j;
        float g0 = a0 + gpa[0]    + gpb[0]    + bsum[j];
        float g1 = a1 + gpa[1024] + gpb[1024] + bsum[j + 1024];
        float g2 = a2 + gpa[2048] + gpb[2048] + bsum[j + 2048];
        float g3 = a3 + gpa[3072] + gpb[3072] + bsum[j + 3072];
        float nd = dmask[b] ? 0.f : 1.f;
        float cp = cprev[(size_t)b * 1024 + j] * nd;
        float si = 1.f / (1.f + expf(-g0));
        float sf = 1.f / (1.f + expf(-g1));
        float so = 1.f / (1.f + expf(-g3));
        float cn = sf * cp + si * tanhf(g2);
        float hn = so * tanhf(cn);
        cout[(size_t)b * 1024 + j] = cn;
        Hout[(size_t)row * 1024 + j] = hn;
    }
}

__global__ __launch_bounds__(256) void heads_k(const float* __restrict__ Hc,
    const float* __restrict__ pw, const float* __restrict__ pb,
    const float* __restrict__ bw, const float* __restrict__ bbias,
    float* __restrict__ out)
{
    __shared__ float red[8][264];
    int n = blockIdx.x, tid = threadIdx.x;
    float4 x4 = *(const float4*)(Hc + (size_t)n * 1024 + (tid << 2));
#pragma unroll
    for (int a = 0; a < 7; a++) {
        float4 w4 = *(const float4*)(pw + (size_t)a * 1024 + (tid << 2));
        red[a][tid] = x4.x * w4.x + x4.y * w4.y + x4.z * w4.z + x4.w * w4.w;
    }
    {
        float4 w4 = *(const float4*)(bw + (tid << 2));
        red[7][tid] = x4.x * w4.x + x4.y * w4.y + x4.z * w4.z + x4.w * w4.w;
    }
    __syncthreads();
    for (int off = 128; off > 0; off >>= 1) {
        if (tid < off) {
#pragma unroll
            for (int a = 0; a < 8; a++) red[a][tid] += red[a][tid + off];
        }
        __syncthreads();
    }
    if (tid == 0) {
        float best = -1e30f; int bi = 0;
        for (int a = 0; a < 7; a++) {
            float L = red[a][0] + pb[a];
            out[n * 7 + a] = L;
            if (L > best) { best = L; bi = a; }
        }
        out[7168 + n] = red[7][0] + bbias[0];
        out[8192 + n] = (float)bi;
    }
}

__global__ __launch_bounds__(256) void final_copy(const float* __restrict__ H0,
    const float* __restrict__ H1, const float* __restrict__ cst, float* __restrict__ out)
{
    int i = blockIdx.x * 256 + threadIdx.x;   // 131072 exact
    if (i < 65536) {
        int l = i >> 15;
        int rem = i & 32767;
        const float* H = l ? H1 : H0;
        out[9216 + i] = H[(size_t)(31 * 32) * 1024 + rem];
    } else {
        out[74752 + (i - 65536)] = cst[i - 65536];
    }
}

extern "C" void kernel_launch(void* const* d_in, const int* in_sizes, int n_in,
                              void* d_out, int out_size, void* d_ws, size_t ws_size,
                              hipStream_t stream)
{
    (void)in_sizes; (void)n_in; (void)out_size; (void)ws_size;
    const float* frame = (const float*)d_in[0];
    const unsigned char* done8 = (const unsigned char*)d_in[1];
    const float* h0   = (const float*)d_in[2];
    const float* c0   = (const float*)d_in[3];
    const float* cw1  = (const float*)d_in[4];
    const float* cb1  = (const float*)d_in[5];
    const float* cw2  = (const float*)d_in[6];
    const float* cb2  = (const float*)d_in[7];
    const float* cw3  = (const float*)d_in[8];
    const float* cb3  = (const float*)d_in[9];
    const float* fw1  = (const float*)d_in[10];
    const float* fb1  = (const float*)d_in[11];
    const float* fw2  = (const float*)d_in[12];
    const float* fb2  = (const float*)d_in[13];
    const float* wih0 = (const float*)d_in[14];
    const float* whh0 = (const float*)d_in[15];
    const float* bih0 = (const float*)d_in[16];
    const float* bhh0 = (const float*)d_in[17];
    const float* wih1 = (const float*)d_in[18];
    const float* whh1 = (const float*)d_in[19];
    const float* bih1 = (const float*)d_in[20];
    const float* bhh1 = (const float*)d_in[21];
    const float* pw   = (const float*)d_in[22];
    const float* pb   = (const float*)d_in[23];
    const float* bw   = (const float*)d_in[24];
    const float* bbias= (const float*)d_in[25];

    float* ws   = (float*)d_ws;
    float* A    = ws;                      // 14,450,688
    float* Bv   = A + 14450688;            //  7,225,344
    float* fc1  = Bv + 7225344;            //  1,048,576
    float* cin  = fc1 + 1048576;           //  1,048,576
    float* H0   = cin + 1048576;           //  1,048,576
    float* H1   = H0 + 1048576;            //  1,048,576
    float* cst  = H1 + 1048576;            //     65,536
    float* bsum = cst + 65536;             //      8,192
    float* wt   = bsum + 8192;             //     19,296
    float* fw1t = A + 8388608;             //  3,964,928 (after conv2f dead)
    float* fcp  = A;                       //  FC partials: up to 8 x 1,048,576 (ends at fw1t)
    float* gxp  = A;                       //  gx partials: 2 x 4,194,304 (after fw1t dead)
    float* conv2f = A;
    float* conv3o = Bv;
    float* out = (float*)d_out;

    repack_w<<<76, 256, 0, stream>>>(cw1, cw2, cw3, wt);
    bsum_k<<<32, 256, 0, stream>>>(bih0, bhh0, bih1, bhh1, bsum);

    for (int ch = 0; ch < 8; ch++) {
        conv1_k<<<1764, 256, 0, stream>>>(frame, wt, cb1, Bv, ch * 128);
        convg_k<42, 21><<<441, 256, 0, stream>>>(Bv, wt + 864, cb2, conv2f, ch * 128 * 441);
    }
    convg_k<21, 11><<<968, 256, 0, stream>>>(conv2f, wt + 10080, cb3, conv3o, 0);
    repack_fw1<<<1024, 256, 0, stream>>>(fw1, fw1t);

    // FC1: M=1024 N=1024 K=3872, Nt=8, splitk 8 (kchunk 496; last chunk 400)
    { dim3 g(64, 1, 8); gemm128<<<g, 256, 0, stream>>>(conv3o, fw1t, fcp, 1048576, 1024, 3872, 8, 496); }
    bias_relu_sum<<<4096, 256, 0, stream>>>(fcp, 1048576, 8, fb1, fc1);
    // FC2: K=1024, splitk 8 (kchunk 128)
    { dim3 g(64, 1, 8); gemm128<<<g, 256, 0, stream>>>(fc1, fw2, fcp, 1048576, 1024, 1024, 8, 128); }
    bias_relu_sum<<<4096, 256, 0, stream>>>(fcp, 1048576, 8, fb2, cin);

    // gx0: M=1024 N=4096 K=1024, Nt=32, splitk 2 -> 512 blocks (fw1t dead now)
    { dim3 g(256, 1, 2); gemm128<<<g, 256, 0, stream>>>(cin, wih0, gxp, 4194304, 4096, 1024, 32, 512); }
    for (int t = 0; t < 32; t++) {
        const float* hp = t ? (H0 + (size_t)(t - 1) * 32768) : h0;
        const float* cp = t ? cst : c0;
        lstm_step<<<512, 256, 0, stream>>>(gxp, gxp + 4194304, whh0, bsum, hp, cp, cst, H0, done8 + t * 32, t);
    }
    // gx1 reuses gx0 partial slots (dead after layer-0 steps)
    { dim3 g(256, 1, 2); gemm128<<<g, 256, 0, stream>>>(H0, wih1, gxp, 4194304, 4096, 1024, 32, 512); }
    for (int t = 0; t < 32; t++) {
        const float* hp = t ? (H1 + (size_t)(t - 1) * 32768) : (h0 + 32768);
        const float* cp = t ? (cst + 32768) : (c0 + 32768);
        lstm_step<<<512, 256, 0, stream>>>(gxp, gxp + 4194304, whh1, bsum + 4096, hp, cp, cst + 32768, H1, done8 + t * 32, t);
    }
    heads_k<<<1024, 256, 0, stream>>>(H1, pw, pb, bw, bbias, out);
    final_copy<<<512, 256, 0, stream>>>(H0, H1, cst, out);
}